// Round 8
// baseline (63467.633 us; speedup 1.0000x reference)
//
#include <hip/hip_runtime.h>

// ---------------------------------------------------------------------------
// ROUND 8: GREEN naive pipeline (round 6, untouched) + on-device MFMA
// self-tests with dur_us as the result channel.
// r7 (zero-LDS MFMA) NaN'd => "LDS staging" theory dead; suspects are the
// MFMA core usage itself vs pipeline glue. Tests T1..T5 each compare a
// 128x128 MFMA tile against naive fp32 results (n=0) on-device; a failed
// test adds a deterministic busy-loop to the timed graph:
//   T1 direct-MFMA proj (K=512,+bias)          fail => +~30ms
//   T2 direct-MFMA energy (vs masked P1)       fail => +~60ms
//   T3 direct-MFMA PV (K=1024, V^T operand)    fail => +~120ms
//   T4 global_load_lds staged core (r2/r4)     fail => +~240ms
//   T5 reg-staged LDS core (r3/r5, LROW=40)    fail => +~480ms
// d_out is written ONLY by the naive path => PASS + absmax 0.125 expected.
// ---------------------------------------------------------------------------

#define RS 0.04419417382415922f  // 1/sqrt(512)

typedef __attribute__((ext_vector_type(8))) short bf16x8;
typedef __attribute__((ext_vector_type(4))) float f32x4;

__device__ __forceinline__ unsigned short f2b(float f) {
  unsigned u = __builtin_bit_cast(unsigned, f);
  unsigned r = (u + 0x7FFFu + ((u >> 16) & 1u)) >> 16;  // RNE
  return (unsigned short)r;
}
__device__ __forceinline__ float b2f(unsigned short h) {
  return __builtin_bit_cast(float, ((unsigned)h) << 16);
}

__global__ void k_fill(float* p, int n, float v) {
  int i = blockIdx.x * blockDim.x + threadIdx.x;
  int stride = gridDim.x * blockDim.x;
  for (; i < n; i += stride) p[i] = v;
}

// ---------------- round-6 naive kernels (GREEN baseline) ----------------
__global__ __launch_bounds__(256) void k_proj(const float* __restrict__ X,
                                              const float* __restrict__ W,
                                              const float* __restrict__ b,
                                              float scale,
                                              float* __restrict__ Y) {
  __shared__ float xs[512];
  int l = blockIdx.x;
  const float* xr = X + (size_t)l * 512;
  for (int i = threadIdx.x; i < 512; i += 256) xs[i] = xr[i];
  __syncthreads();
  for (int j = 0; j < 16; ++j) {
    int o = j * 256 + threadIdx.x;
    const float* wr = W + (size_t)o * 512;
    float acc = 0.f;
#pragma unroll 8
    for (int k = 0; k < 512; ++k) acc += xs[k] * wr[k];
    Y[(size_t)l * 4096 + o] = (acc + b[o]) * scale;
  }
}

__global__ __launch_bounds__(256) void k_energy(const float* __restrict__ Qn,
                                                const float* __restrict__ Kn,
                                                const int* __restrict__ mask,
                                                int h, float* __restrict__ P1) {
  __shared__ float qs[512];
  int q = blockIdx.x;
  const float* qr = Qn + (size_t)q * 4096 + h * 512;
  for (int i = threadIdx.x; i < 512; i += 256) qs[i] = qr[i];
  __syncthreads();
  for (int j = 0; j < 4; ++j) {
    int l = j * 256 + threadIdx.x;
    const float* kr = Kn + (size_t)l * 4096 + h * 512;
    float acc = 0.f;
#pragma unroll 8
    for (int k = 0; k < 512; ++k) acc += qs[k] * kr[k];
    P1[(size_t)q * 1024 + l] = mask[(size_t)q * 1024 + l] ? acc : 0.f;
  }
}

__global__ __launch_bounds__(256) void k_pv(const float* __restrict__ P1,
                                            const float* __restrict__ Vn,
                                            int h, float* __restrict__ Atn) {
  __shared__ float ps[1024];
  int q = blockIdx.x;
  const float* pr = P1 + (size_t)q * 1024;
  for (int i = threadIdx.x; i < 1024; i += 256) ps[i] = pr[i];
  __syncthreads();
  for (int j = 0; j < 2; ++j) {
    int e = j * 256 + threadIdx.x;
    const float* vb = Vn + h * 512 + e;
    float acc = 0.f;
    for (int l = 0; l < 1024; ++l) acc += ps[l] * vb[(size_t)l * 4096];
    float* dst = &Atn[(size_t)q * 512 + e];
    *dst = (h == 0 ? 0.f : *dst) + acc;
  }
}

__global__ __launch_bounds__(256) void k_final(const float* __restrict__ Atn,
                                               const float* __restrict__ Wo,
                                               const float* __restrict__ bo,
                                               float* __restrict__ out) {
  __shared__ float as_[512];
  int q = blockIdx.x;
  const float* ar = Atn + (size_t)q * 512;
  for (int i = threadIdx.x; i < 512; i += 256) as_[i] = ar[i];
  __syncthreads();
  for (int j = 0; j < 2; ++j) {
    int o = j * 256 + threadIdx.x;
    const float* wr = Wo + (size_t)o * 512;
    float acc = 0.f;
#pragma unroll 8
    for (int k = 0; k < 512; ++k) acc += as_[k] * wr[k];
    out[(size_t)q * 512 + o] = acc + bo[o];
  }
}

// ---------------- self-test machinery ----------------
__global__ void k_zeroflags(int* f) {
  if (threadIdx.x < 8) f[threadIdx.x] = 0;
}

// dst[r][c] = f2b(src[r*lds + c]); packed [rows][K]
__global__ void k_pack(const float* __restrict__ src, int lds,
                       unsigned short* __restrict__ dst, int total, int K) {
  int i = blockIdx.x * blockDim.x + threadIdx.x;
  if (i >= total) return;
  int r = i / K, c = i % K;
  dst[i] = f2b(src[(size_t)r * lds + c]);
}
// dst[r][c] = f2b(src[c*lds + r])  (transpose pack)
__global__ void k_packT(const float* __restrict__ src, int lds,
                        unsigned short* __restrict__ dst, int total, int K) {
  int i = blockIdx.x * blockDim.x + threadIdx.x;
  if (i >= total) return;
  int r = i / K, c = i % K;
  dst[i] = f2b(src[(size_t)c * lds + r]);
}

// T1/T2/T3 core: out[128][128] fp32 = A[128][K] @ B[128][K]^T (+bias)
// Direct global->VGPR fragments (r7 structure). grid(2,2), 4 waves/block.
__global__ __launch_bounds__(256) void k_mmt(
    const unsigned short* __restrict__ A, const unsigned short* __restrict__ B,
    const float* __restrict__ bias, float* __restrict__ out, int K) {
  const int tid = threadIdx.x;
  const int w = tid >> 6, lane = tid & 63;
  const int l15 = lane & 15, l4 = lane >> 4;
  const int bx = blockIdx.x, by = blockIdx.y;

  f32x4 acc[4];
#pragma unroll
  for (int f = 0; f < 4; ++f) acc[f] = (f32x4){0.f, 0.f, 0.f, 0.f};

  const unsigned short* ar = A + (size_t)(bx * 64 + w * 16 + l15) * K + l4 * 8;
  const unsigned short* br[4];
#pragma unroll
  for (int f = 0; f < 4; ++f)
    br[f] = B + (size_t)(by * 64 + f * 16 + l15) * K + l4 * 8;

  for (int kc = 0; kc < K / 32; ++kc) {
    bf16x8 av = *(const bf16x8*)(ar + kc * 32);
#pragma unroll
    for (int f = 0; f < 4; ++f)
      acc[f] = __builtin_amdgcn_mfma_f32_16x16x32_bf16(
          av, *(const bf16x8*)(br[f] + kc * 32), acc[f], 0, 0, 0);
  }
#pragma unroll
  for (int f = 0; f < 4; ++f) {
    int c_ = by * 64 + f * 16 + l15;
    float bb = bias ? bias[c_] : 0.f;
#pragma unroll
    for (int r = 0; r < 4; ++r) {
      int r_ = bx * 64 + w * 16 + l4 * 4 + r;
      out[r_ * 128 + c_] = acc[f][r] + bb;
    }
  }
}

#define GLD16(gp, sp)                                              \
  __builtin_amdgcn_global_load_lds(                                \
      (const __attribute__((address_space(1))) void*)(gp),         \
      (__attribute__((address_space(3))) void*)(sp), 16, 0, 0)

// T4: exact r2/r4 GLD16-staged core. 128x128 out, K=512, single block.
__global__ __launch_bounds__(256) void k_mmt_lds(
    const unsigned short* __restrict__ A, const unsigned short* __restrict__ B,
    const float* __restrict__ bias, float* __restrict__ out) {
  __shared__ short As[128 * 32];
  __shared__ short Bs[128 * 32];
  const int tid = threadIdx.x;
  const int wid = tid >> 6, lane = tid & 63;
  const int wr = wid >> 1, wc = wid & 1;
  const int l15 = lane & 15, l4 = lane >> 4;

  f32x4 acc[4][4];
#pragma unroll
  for (int i = 0; i < 4; ++i)
#pragma unroll
    for (int j = 0; j < 4; ++j) acc[i][j] = (f32x4){0.f, 0.f, 0.f, 0.f};

  for (int kc = 0; kc < 16; ++kc) {
#pragma unroll
    for (int is = 0; is < 2; ++is) {
      int c = is * 256 + tid;
      int row = c >> 2;
      int col = (c & 3) << 3;
      GLD16(A + (size_t)row * 512 + kc * 32 + col,
            (char*)As + is * 4096 + wid * 1024);
      GLD16(B + (size_t)row * 512 + kc * 32 + col,
            (char*)Bs + is * 4096 + wid * 1024);
    }
    __syncthreads();
    bf16x8 af[4], bf_[4];
#pragma unroll
    for (int f = 0; f < 4; ++f) {
      af[f] = *(const bf16x8*)((const char*)As +
                               ((wr * 64 + f * 16 + l15) << 6) + (l4 << 4));
      bf_[f] = *(const bf16x8*)((const char*)Bs +
                                ((wc * 64 + f * 16 + l15) << 6) + (l4 << 4));
    }
#pragma unroll
    for (int mf = 0; mf < 4; ++mf)
#pragma unroll
      for (int nf = 0; nf < 4; ++nf)
        acc[mf][nf] = __builtin_amdgcn_mfma_f32_16x16x32_bf16(
            af[mf], bf_[nf], acc[mf][nf], 0, 0, 0);
    __syncthreads();
  }
#pragma unroll
  for (int nf = 0; nf < 4; ++nf) {
    int c_ = wc * 64 + nf * 16 + l15;
    float bb = bias ? bias[c_] : 0.f;
#pragma unroll
    for (int mf = 0; mf < 4; ++mf)
#pragma unroll
      for (int r = 0; r < 4; ++r) {
        int r_ = wr * 64 + mf * 16 + l4 * 4 + r;
        out[r_ * 128 + c_] = acc[mf][nf][r] + bb;
      }
  }
}

// T5: exact r3/r5 reg-staged core (LROW=40 padding). 128x128, K=512, 1 block.
#define LROW 40
__global__ __launch_bounds__(256) void k_mmt_reg(
    const unsigned short* __restrict__ A, const unsigned short* __restrict__ B,
    const float* __restrict__ bias, float* __restrict__ out) {
  __shared__ short As[128 * LROW];
  __shared__ short Bs[128 * LROW];
  const int tid = threadIdx.x;
  const int lane = tid & 63;
  const int wid = tid >> 6;
  const int wr = wid >> 1, wc = wid & 1;
  const int l15 = lane & 15, l4 = lane >> 4;

  f32x4 acc[4][4];
#pragma unroll
  for (int i = 0; i < 4; ++i)
#pragma unroll
    for (int j = 0; j < 4; ++j) acc[i][j] = (f32x4){0.f, 0.f, 0.f, 0.f};

  const int c0_ = tid, c1_ = 256 + tid;
  for (int kc = 0; kc < 16; ++kc) {
    {
      int r0_ = c0_ >> 2, k0_ = (c0_ & 3) << 3;
      int r1_ = c1_ >> 2, k1_ = (c1_ & 3) << 3;
      bf16x8 a0 = *(const bf16x8*)(A + (size_t)r0_ * 512 + kc * 32 + k0_);
      bf16x8 b0 = *(const bf16x8*)(B + (size_t)r0_ * 512 + kc * 32 + k0_);
      bf16x8 a1 = *(const bf16x8*)(A + (size_t)r1_ * 512 + kc * 32 + k1_);
      bf16x8 b1 = *(const bf16x8*)(B + (size_t)r1_ * 512 + kc * 32 + k1_);
      *(bf16x8*)(As + r0_ * LROW + k0_) = a0;
      *(bf16x8*)(Bs + r0_ * LROW + k0_) = b0;
      *(bf16x8*)(As + r1_ * LROW + k1_) = a1;
      *(bf16x8*)(Bs + r1_ * LROW + k1_) = b1;
    }
    __syncthreads();
    bf16x8 af[4], bf_[4];
#pragma unroll
    for (int f = 0; f < 4; ++f) {
      af[f] = *(const bf16x8*)(As + (wr * 64 + f * 16 + l15) * LROW + l4 * 8);
      bf_[f] = *(const bf16x8*)(Bs + (wc * 64 + f * 16 + l15) * LROW + l4 * 8);
    }
#pragma unroll
    for (int mf = 0; mf < 4; ++mf)
#pragma unroll
      for (int nf = 0; nf < 4; ++nf)
        acc[mf][nf] = __builtin_amdgcn_mfma_f32_16x16x32_bf16(
            af[mf], bf_[nf], acc[mf][nf], 0, 0, 0);
    __syncthreads();
  }
#pragma unroll
  for (int nf = 0; nf < 4; ++nf) {
    int c_ = wc * 64 + nf * 16 + l15;
    float bb = bias ? bias[c_] : 0.f;
#pragma unroll
    for (int mf = 0; mf < 4; ++mf)
#pragma unroll
      for (int r = 0; r < 4; ++r) {
        int r_ = wr * 64 + mf * 16 + l4 * 4 + r;
        out[r_ * 128 + c_] = acc[mf][nf][r] + bb;
      }
  }
}

// compare out[128][128] vs ref (leading dim ldr); NaN-safe; optional mask skip
__global__ void k_cmp(const float* __restrict__ out,
                      const float* __restrict__ ref, int ldr,
                      const int* __restrict__ mask, float tol, int* flag) {
  int i = blockIdx.x * 256 + threadIdx.x;  // 16384 total
  int r = i >> 7, c = i & 127;
  if (mask && mask[(size_t)r * 1024 + c] == 0) return;
  float d = fabsf(out[i] - ref[(size_t)r * ldr + c]);
  if (!(d <= tol)) atomicOr(flag, 1);
}

// deterministic busy-loop if *flag != 0 (~reps*36 cycles)
__global__ void k_busy(const int* __restrict__ flag, int reps,
                       float* __restrict__ sink) {
  if (*flag == 0) return;
  float x = (float)threadIdx.x * 1e-9f;
  for (int r = 0; r < reps; ++r) {
    x = fmaf(x, 1.0000001f, 1e-9f);
    x = fmaf(x, 1.0000001f, 1e-9f);
    x = fmaf(x, 1.0000001f, 1e-9f);
    x = fmaf(x, 1.0000001f, 1e-9f);
    x = fmaf(x, 1.0000001f, 1e-9f);
    x = fmaf(x, 1.0000001f, 1e-9f);
    x = fmaf(x, 1.0000001f, 1e-9f);
    x = fmaf(x, 1.0000001f, 1e-9f);
  }
  if (x == 12345.678f) *sink = x;
}

extern "C" void kernel_launch(void* const* d_in, const int* in_sizes, int n_in,
                              void* d_out, int out_size, void* d_ws,
                              size_t ws_size, hipStream_t stream) {
  const float* values = (const float*)d_in[0];
  const float* keys = (const float*)d_in[1];
  const float* query = (const float*)d_in[2];
  const int* maskI = (const int*)d_in[4];
  const float* Wv = (const float*)d_in[5];
  const float* bv = (const float*)d_in[6];
  const float* Wk = (const float*)d_in[7];
  const float* bk = (const float*)d_in[8];
  const float* Wq = (const float*)d_in[9];
  const float* bq = (const float*)d_in[10];
  const float* Wo = (const float*)d_in[11];
  const float* bo = (const float*)d_in[12];
  float* dout = (float*)d_out;

  const int exp_sizes[13] = {4194304, 4194304, 4194304, 1024, 8388608,
                             2097152, 4096,    2097152, 4096, 2097152,
                             4096,    262144,  512};
  bool ok = (n_in == 13);
  if (ok)
    for (int i = 0; i < 13; ++i)
      if (in_sizes[i] != exp_sizes[i]) ok = false;
  if (!ok) {
    k_fill<<<512, 256, 0, stream>>>(dout, out_size, 1000.f);
    return;
  }

  const size_t SQN = 16777216;  // 1024*4096 fp32
  const size_t SP1 = 4194304;   // 1024*1024 fp32
  const size_t need = 3 * SQN + SP1 + 2097152;
  if (ws_size < need) {
    k_fill<<<512, 256, 0, stream>>>(dout, out_size, 2000.f);
    return;
  }
  char* w = (char*)d_ws;
  float* Qn = (float*)(w);
  float* Kn = (float*)(w + SQN);
  float* Vn = (float*)(w + 2 * SQN);
  float* P1 = (float*)(w + 3 * SQN);
  char* scr = w + 3 * SQN + SP1;  // 2MB region
  float* Atn = (float*)scr;       // comparisons read rows 0..127 only
  unsigned short* tA = (unsigned short*)(scr + 524288);   // 256KB slot
  unsigned short* tB = (unsigned short*)(scr + 786432);   // 256KB slot
  float* outS = (float*)(scr + 1048576);                  // 64KB
  int* flags = (int*)(scr + 1114112);
  float* sink = (float*)(scr + 1114144);

  // ---------------- GREEN naive pipeline (round 6) ----------------
  for (int n = 0; n < 8; ++n) {
    const size_t xoff = (size_t)n * 1024 * 512;
    k_proj<<<1024, 256, 0, stream>>>(values + xoff, Wv, bv, 1.0f, Vn);
    k_proj<<<1024, 256, 0, stream>>>(keys + xoff, Wk, bk, 1.0f, Kn);
    k_proj<<<1024, 256, 0, stream>>>(query + xoff, Wq, bq, RS, Qn);
    for (int h = 0; h < 8; ++h) {
      k_energy<<<1024, 256, 0, stream>>>(Qn, Kn,
                                         maskI + (size_t)n * 1024 * 1024, h,
                                         P1);
      k_pv<<<1024, 256, 0, stream>>>(P1, Vn, h, Atn);
    }
    k_final<<<1024, 256, 0, stream>>>(Atn, Wo, bo,
                                      dout + (size_t)n * 1024 * 512);
  }

  // ---------------- self-tests (n=0 data) ----------------
  // recompute n=0 naive intermediates
  k_proj<<<1024, 256, 0, stream>>>(values, Wv, bv, 1.0f, Vn);
  k_proj<<<1024, 256, 0, stream>>>(keys, Wk, bk, 1.0f, Kn);
  k_proj<<<1024, 256, 0, stream>>>(query, Wq, bq, RS, Qn);
  k_energy<<<1024, 256, 0, stream>>>(Qn, Kn, maskI, 0, P1);
  k_pv<<<1024, 256, 0, stream>>>(P1, Vn, 0, Atn);  // Atn = h0 partial
  k_zeroflags<<<1, 64, 0, stream>>>(flags);

  // T1: direct MFMA V-proj tile: x[0:128] @ Wv[0:128]^T + bv vs Vn
  k_pack<<<256, 256, 0, stream>>>(values, 512, tA, 65536, 512);
  k_pack<<<256, 256, 0, stream>>>(Wv, 512, tB, 65536, 512);
  k_mmt<<<dim3(2, 2), 256, 0, stream>>>(tA, tB, bv, outS, 512);
  k_cmp<<<64, 256, 0, stream>>>(outS, Vn, 4096, nullptr, 0.15f, flags + 0);
  k_busy<<<1, 64, 0, stream>>>(flags + 0, 2000000, sink);  // +~30ms

  // T2: direct MFMA energy tile (h=0): Qn[0:128] @ Kn[0:128]^T vs P1 (masked)
  k_pack<<<256, 256, 0, stream>>>(Qn, 4096, tA, 65536, 512);
  k_pack<<<256, 256, 0, stream>>>(Kn, 4096, tB, 65536, 512);
  k_mmt<<<dim3(2, 2), 256, 0, stream>>>(tA, tB, nullptr, outS, 512);
  k_cmp<<<64, 256, 0, stream>>>(outS, P1, 1024, maskI, 0.15f, flags + 1);
  k_busy<<<1, 64, 0, stream>>>(flags + 1, 4000000, sink);  // +~60ms

  // T3: direct MFMA PV tile: P1[0:128] @ (V^T)[0:128]^T vs Atn (h0 partial)
  k_pack<<<512, 256, 0, stream>>>(P1, 1024, tA, 131072, 1024);
  k_packT<<<512, 256, 0, stream>>>(Vn, 4096, tB, 131072, 1024);
  k_mmt<<<dim3(2, 2), 256, 0, stream>>>(tA, tB, nullptr, outS, 1024);
  k_cmp<<<64, 256, 0, stream>>>(outS, Atn, 512, nullptr, 0.35f, flags + 2);
  k_busy<<<1, 64, 0, stream>>>(flags + 2, 8000000, sink);  // +~120ms

  // T4: GLD16-staged core (r2/r4) on T1 operands
  k_pack<<<256, 256, 0, stream>>>(values, 512, tA, 65536, 512);
  k_pack<<<256, 256, 0, stream>>>(Wv, 512, tB, 65536, 512);
  k_mmt_lds<<<1, 256, 0, stream>>>(tA, tB, bv, outS);
  k_cmp<<<64, 256, 0, stream>>>(outS, Vn, 4096, nullptr, 0.15f, flags + 3);
  k_busy<<<1, 64, 0, stream>>>(flags + 3, 16000000, sink);  // +~240ms

  // T5: reg-staged core (r3/r5) on T1 operands
  k_mmt_reg<<<1, 256, 0, stream>>>(tA, tB, bv, outS);
  k_cmp<<<64, 256, 0, stream>>>(outS, Vn, 4096, nullptr, 0.15f, flags + 4);
  k_busy<<<1, 64, 0, stream>>>(flags + 4, 32000000, sink);  // +~480ms
}